// Round 13
// baseline (90.154 us; speedup 1.0000x reference)
//
#include <hip/hip_runtime.h>
#include <math.h>

#define D 512
#define NC 64
#define NQ 2048

typedef unsigned short u16;
typedef __attribute__((ext_vector_type(8))) short bf8;
typedef __attribute__((ext_vector_type(4))) float f4;

// ---- workspace float offsets ----
#define OFF_S    0
#define OFF_LH   32                       // 512x512 u16 L hi/lo
#define OFF_LL   (OFF_LH + 131072)
#define OFF_DIH  (OFF_LL + 131072)        // 8 x 64x64 u16 Dinv64 blocks (compact)
#define OFF_DIL  (OFF_DIH + 16384)
#define OFF_YYH  (OFF_DIL + 16384)        // 2560x512 u16 YY hi; lo only rows>=512
#define OFF_YYL  (OFF_YYH + 655360)
#define OFF_AQ   (OFF_YYL + 655360)       // 2048 fp32
#define OFF_GRAM (OFF_AQ + NQ)            // 64*28 fp32 packed upper-tri 7x7 Grams

#define GIX(i, j) ((i) * 7 - (i) * ((i) + 1) / 2 + (j))

__device__ inline float wred(float v) {
#pragma unroll
  for (int off = 32; off; off >>= 1) v += __shfl_down(v, off);
  return v;
}

// split fp32 into hi bf16 (truncated, so v-hi is exact) + lo bf16 (RN)
__device__ inline void split2(float v, u16& h, u16& l) {
  unsigned u = __float_as_uint(v);
  h = (u16)(u >> 16);
  float hf = __uint_as_float(u & 0xFFFF0000u);
  float r = v - hf;
  unsigned ru = __float_as_uint(r);
  l = (u16)((ru + 0x7FFFu + ((ru >> 16) & 1u)) >> 16);
}

__device__ inline void split4(float a0, float a1, float a2, float a3,
                              ushort4& h, ushort4& l) {
  u16 hh, ll;
  split2(a0, hh, ll); h.x = hh; l.x = ll;
  split2(a1, hh, ll); h.y = hh; l.y = ll;
  split2(a2, hh, ll); h.z = hh; l.z = ll;
  split2(a3, hh, ll); h.w = hh; l.w = ll;
}

__device__ inline float recon(u16 h, u16 l) {
  return __uint_as_float((unsigned)h << 16) + __uint_as_float((unsigned)l << 16);
}

#define MPAD 68
template <int N>
__device__ inline void lds_mm(float (*M)[MPAD], int ar, int ac, int br, int bc,
                              int cr, int cc, bool neg) {
  const int T = N / 16;
  int tx = (threadIdx.x & 15) * T, ty = (threadIdx.x >> 4) * T;
  float acc[T][T];
#pragma unroll
  for (int i = 0; i < T; ++i)
#pragma unroll
    for (int j = 0; j < T; ++j) acc[i][j] = 0.f;
#pragma unroll 8
  for (int k = 0; k < N; ++k) {
    float a[T], b[T];
#pragma unroll
    for (int i = 0; i < T; ++i) a[i] = M[ar + ty + i][ac + k];
#pragma unroll
    for (int j = 0; j < T; ++j) b[j] = M[br + k][bc + tx + j];
#pragma unroll
    for (int i = 0; i < T; ++i)
#pragma unroll
      for (int j = 0; j < T; ++j) acc[i][j] += a[i] * b[j];
  }
#pragma unroll
  for (int i = 0; i < T; ++i)
#pragma unroll
    for (int j = 0; j < T; ++j)
      M[cr + ty + i][cc + tx + j] = neg ? -acc[i][j] : acc[i][j];
}

// In-LDS 64x64 lower-tri inversion; scratch cleaned -> exact inverse, zero upper.
__device__ inline void inv64(float (*M)[MPAD], int tid) {
  {
    float x[16];
    int q = tid >> 4, col = tid & 15;
    if (tid < 64) {
      int b = q << 4;
#pragma unroll
      for (int i = 0; i < 16; ++i) {
        float acc = 0.f;
#pragma unroll
        for (int k = 0; k < i; ++k) acc += M[b + i][b + k] * x[k];
        x[i] = (((i == col) ? 1.f : 0.f) - acc) / M[b + i][b + i];
      }
    }
    __syncthreads();
    if (tid < 64) {
      int b = q << 4;
#pragma unroll
      for (int i = 0; i < 16; ++i) M[b + i][b + col] = x[i];
    }
    __syncthreads();
  }
  for (int pp = 0; pp < 2; ++pp) {
    int r0 = 32 * pp;
    lds_mm<16>(M, r0 + 16, r0, r0, r0, r0, r0 + 16, false);
  }
  __syncthreads();
  for (int pp = 0; pp < 2; ++pp) {
    int r0 = 32 * pp;
    lds_mm<16>(M, r0 + 16, r0 + 16, r0, r0 + 16, r0 + 16, r0, true);
  }
  __syncthreads();
  for (int idx = tid; idx < 512; idx += 256) {     // zero level-16 scratch
    int t2 = idx >> 8, r = (idx >> 4) & 15, c = idx & 15;
    M[32 * t2 + r][32 * t2 + 16 + c] = 0.f;
  }
  __syncthreads();
  lds_mm<32>(M, 32, 0, 0, 0, 0, 32, false);
  __syncthreads();
  lds_mm<32>(M, 32, 32, 0, 32, 32, 0, true);
  __syncthreads();
  for (int idx = tid; idx < 1024; idx += 256) {    // zero level-32 scratch
    int r = idx >> 5, c = idx & 31;
    M[r][32 + c] = 0.f;
  }
  __syncthreads();
}

// Prep (265 blocks): 0..7 Dinv64 diag -> DIAG (h/l); 8..263 L-split; 264 scalars.
__global__ __launch_bounds__(256) void k_prep(const float* __restrict__ diag,
                                              const float* __restrict__ low,
                                              const float* __restrict__ kp,
                                              const float* __restrict__ nup,
                                              u16* __restrict__ Lh, u16* __restrict__ Ll,
                                              u16* __restrict__ DIh, u16* __restrict__ DIl,
                                              float* __restrict__ S) {
  __shared__ float M[64][MPAD];
  int bid = blockIdx.x, tid = threadIdx.x;
  if (bid < 8) {
    int p = bid * 64;
    for (int idx = tid; idx < 4096; idx += 256) {
      int r = idx >> 6, c = idx & 63;
      float v;
      if (r == c)      v = fabsf(diag[p + r]);
      else if (r > c)  v = low[(size_t)(p + r) * D + p + c];
      else             v = 0.f;
      M[r][c] = v;
    }
    __syncthreads();
    inv64(M, tid);
    for (int idx = tid; idx < 1024; idx += 256) {
      int r = idx >> 4, c4 = (idx & 15) << 2;
      ushort4 hh, ll;
      split4(M[r][c4 + 0], M[r][c4 + 1], M[r][c4 + 2], M[r][c4 + 3], hh, ll);
      size_t gi = (size_t)bid * 4096 + r * 64 + c4;
      *reinterpret_cast<ushort4*>(DIh + gi) = hh;
      *reinterpret_cast<ushort4*>(DIl + gi) = ll;
    }
  } else if (bid < 264) {
    int t = (bid - 8) * 1024 + tid * 4;
    int i = t >> 9, j = t & 511;
    float4 lv = *reinterpret_cast<const float4*>(low + t);
    float a[4] = {lv.x, lv.y, lv.z, lv.w};
    float dv = diag[i];
    float o[4];
#pragma unroll
    for (int e = 0; e < 4; ++e) {
      int jj = j + e;
      o[e] = (i == jj) ? fabsf(dv) : (i > jj ? a[e] : 0.f);
    }
    ushort4 hh, ll;
    split4(o[0], o[1], o[2], o[3], hh, ll);
    *reinterpret_cast<ushort4*>(Lh + t) = hh;
    *reinterpret_cast<ushort4*>(Ll + t) = ll;
  } else {
    if (tid >= 64) return;
    float part = 0.f;
    for (int i = tid; i < D; i += 64) part += logf(fabsf(diag[i]));
    part = wred(part);
    if (tid != 0) return;
    float lda = 2.f * part;
    float kappa = kp[0], nu = nup[0];
    float kn = fabsf(kappa) + 1e-6f + 5.0f;
    float sp = fmaxf(nu, (float)(D - 1) + 1e-6f) + 5.0f - (float)D + 2.0f;
    float bias_shared = lgammaf(0.5f * (sp + (float)D)) - lgammaf(0.5f * sp)
                      - 0.5f * (float)D * logf(sp);
    float scale = kn * sp / (kn + 1.0f);
    S[3] = bias_shared;
    S[8] = 1.f / scale;
    S[9] = (float)D * logf(scale) + lda;
    S[10] = 0.5f * (sp + (float)D);
    S[11] = 1.f / sp;
  }
}

// Fused build+solve: block owns 32 rows of [Ubp(512); Xq(2048)] in LDS (h/l).
// Solves L*YY^T = AB^T in 8 steps: YY_i = (AB_i - sum_k YY_k L_ik^T) Dinv_i^T,
// all MFMA split-bf16 3-pass. Fused: YYh/(YYl) global, Gram (UW blocks, from
// per-step fp32 staging, exclusive writes), aq (Xq blocks).
__global__ __launch_bounds__(256) void k_fsolve(const u16* __restrict__ Lh,
                                                const u16* __restrict__ Ll,
                                                const u16* __restrict__ DIh,
                                                const u16* __restrict__ DIl,
                                                const float* __restrict__ Xs,
                                                const float* __restrict__ Xq,
                                                const float* __restrict__ m,
                                                const float* __restrict__ kp,
                                                u16* __restrict__ YYh, u16* __restrict__ YYl,
                                                float* __restrict__ Gram,
                                                float* __restrict__ aq) {
  __shared__ __align__(16) u16 Yhs[32][536];
  __shared__ __align__(16) u16 Yls[32][536];
  __shared__ __align__(16) float Ts[32][68];
  __shared__ float asq[32];
  int bid = blockIdx.x, tid = threadIdx.x;
  int w = tid >> 6, lane = tid & 63;
  int lr = lane & 15, kq = lane >> 4;
  int mi = w >> 1, nb0 = (w & 1) * 2;
  bool isU = bid < 16;
  int row0 = bid * 32;
  // ---- init: build AB rows directly from inputs ----
  if (isU) {
    float kappa = kp[0];
    float kn = fabsf(kappa) + 1e-6f + 5.0f;
    float xw = 5.0f / kn;
    float mw = fabsf(kappa + 1e-6f) / kn;
    float sw = sqrtf((fabsf(kappa) + 1e-6f) / kn);
    const float is5 = 0.44721359549995793f;
    for (int d = tid; d < D; d += 256) {
      float mv = m[d];
#pragma unroll
      for (int cl = 0; cl < 4; ++cl) {
        int c = bid * 4 + cl;
        float x0 = Xs[(size_t)(c * 5 + 0) * D + d];
        float x1 = Xs[(size_t)(c * 5 + 1) * D + d];
        float x2 = Xs[(size_t)(c * 5 + 2) * D + d];
        float x3 = Xs[(size_t)(c * 5 + 3) * D + d];
        float x4 = Xs[(size_t)(c * 5 + 4) * D + d];
        float xm = (x0 + x1 + x2 + x3 + x4) * 0.2f;
        float rows[8];
        rows[0] = x0 * is5; rows[1] = x1 * is5; rows[2] = x2 * is5;
        rows[3] = x3 * is5; rows[4] = x4 * is5;
        rows[5] = sw * (xm - mv);
        rows[6] = mw * mv + xw * xm;
        rows[7] = 0.f;
#pragma unroll
        for (int s = 0; s < 8; ++s) {
          u16 hh, ll; split2(rows[s], hh, ll);
          Yhs[cl * 8 + s][d] = hh; Yls[cl * 8 + s][d] = ll;
        }
      }
    }
  } else {
    int q0 = row0 - 512;
    for (int idx = tid; idx < 32 * 128; idx += 256) {
      int r = idx >> 7, c4 = (idx & 127) << 2;
      float4 v = *reinterpret_cast<const float4*>(&Xq[(size_t)(q0 + r) * D + c4]);
      u16 hh, ll;
      split2(v.x, hh, ll); Yhs[r][c4 + 0] = hh; Yls[r][c4 + 0] = ll;
      split2(v.y, hh, ll); Yhs[r][c4 + 1] = hh; Yls[r][c4 + 1] = ll;
      split2(v.z, hh, ll); Yhs[r][c4 + 2] = hh; Yls[r][c4 + 2] = ll;
      split2(v.w, hh, ll); Yhs[r][c4 + 3] = hh; Yls[r][c4 + 3] = ll;
    }
    if (tid < 32) asq[tid] = 0.f;
  }
  __syncthreads();
  const int PI[28] = {0,0,0,0,0,0,0, 1,1,1,1,1,1, 2,2,2,2,2, 3,3,3,3, 4,4,4, 5,5, 6};
  const int PJ[28] = {0,1,2,3,4,5,6, 1,2,3,4,5,6, 2,3,4,5,6, 3,4,5,6, 4,5,6, 5,6, 6};
  int gcl = tid / 28, gp = tid % 28;   // Gram pair ownership (tid<112)
  float gacc = 0.f;
  float sqs[4] = {0.f, 0.f, 0.f, 0.f};
  for (int i = 0; i < 8; ++i) {
    // S = sum_{k<i} YY_k . L_ik^T  (NT, A from LDS, B from global L)
    f4 acc[2];
    acc[0] = (f4){0.f, 0.f, 0.f, 0.f};
    acc[1] = (f4){0.f, 0.f, 0.f, 0.f};
    for (int k = 0; k < i; ++k) {
#pragma unroll
      for (int kk = 0; kk < 2; ++kk) {
        int co = 64 * k + kk * 32 + kq * 8;
        bf8 ah = *reinterpret_cast<const bf8*>(&Yhs[16 * mi + lr][co]);
        bf8 al = *reinterpret_cast<const bf8*>(&Yls[16 * mi + lr][co]);
#pragma unroll
        for (int nf = 0; nf < 2; ++nf) {
          size_t gb = (size_t)(64 * i + (nb0 + nf) * 16 + lr) * D + co;
          bf8 bh = *reinterpret_cast<const bf8*>(Lh + gb);
          bf8 bl = *reinterpret_cast<const bf8*>(Ll + gb);
          acc[nf] = __builtin_amdgcn_mfma_f32_16x16x32_bf16(ah, bh, acc[nf], 0, 0, 0);
          acc[nf] = __builtin_amdgcn_mfma_f32_16x16x32_bf16(al, bh, acc[nf], 0, 0, 0);
          acc[nf] = __builtin_amdgcn_mfma_f32_16x16x32_bf16(ah, bl, acc[nf], 0, 0, 0);
        }
      }
    }
    // T = AB_i - S  (fp32 staging)
#pragma unroll
    for (int nf = 0; nf < 2; ++nf)
#pragma unroll
      for (int reg = 0; reg < 4; ++reg) {
        int rl = 16 * mi + kq * 4 + reg, cl_ = (nb0 + nf) * 16 + lr;
        float ab = recon(Yhs[rl][64 * i + cl_], Yls[rl][64 * i + cl_]);
        Ts[rl][cl_] = ab - acc[nf][reg];
      }
    __syncthreads();
    // YY_i = T . Dinv_i^T  (A from Ts fp32 split on read, B from DIAG)
    f4 acc2[2];
    acc2[0] = (f4){0.f, 0.f, 0.f, 0.f};
    acc2[1] = (f4){0.f, 0.f, 0.f, 0.f};
#pragma unroll
    for (int kk = 0; kk < 2; ++kk) {
      int co = kk * 32 + kq * 8;
      float4 t0 = *reinterpret_cast<const float4*>(&Ts[16 * mi + lr][co]);
      float4 t1 = *reinterpret_cast<const float4*>(&Ts[16 * mi + lr][co + 4]);
      float tv[8] = {t0.x, t0.y, t0.z, t0.w, t1.x, t1.y, t1.z, t1.w};
      bf8 ah2, al2;
#pragma unroll
      for (int e = 0; e < 8; ++e) {
        u16 hh, ll; split2(tv[e], hh, ll);
        ah2[e] = (short)hh; al2[e] = (short)ll;
      }
#pragma unroll
      for (int nf = 0; nf < 2; ++nf) {
        size_t db = (size_t)i * 4096 + ((nb0 + nf) * 16 + lr) * 64 + co;
        bf8 bh = *reinterpret_cast<const bf8*>(DIh + db);
        bf8 bl = *reinterpret_cast<const bf8*>(DIl + db);
        acc2[nf] = __builtin_amdgcn_mfma_f32_16x16x32_bf16(ah2, bh, acc2[nf], 0, 0, 0);
        acc2[nf] = __builtin_amdgcn_mfma_f32_16x16x32_bf16(al2, bh, acc2[nf], 0, 0, 0);
        acc2[nf] = __builtin_amdgcn_mfma_f32_16x16x32_bf16(ah2, bl, acc2[nf], 0, 0, 0);
      }
    }
    __syncthreads();   // all Ts reads done before overwrite
    // write back block i (LDS + global), stage fp32 for Gram / accumulate aq
#pragma unroll
    for (int nf = 0; nf < 2; ++nf)
#pragma unroll
      for (int reg = 0; reg < 4; ++reg) {
        int rl = 16 * mi + kq * 4 + reg, cl_ = (nb0 + nf) * 16 + lr;
        float v = acc2[nf][reg];
        u16 hh, ll; split2(v, hh, ll);
        Yhs[rl][64 * i + cl_] = hh; Yls[rl][64 * i + cl_] = ll;
        size_t gi = (size_t)(row0 + rl) * D + 64 * i + cl_;
        YYh[gi] = hh;
        if (!isU) { YYl[gi] = ll; sqs[reg] += v * v; }
        else Ts[rl][cl_] = v;
      }
    if (isU) {
      __syncthreads();
      if (tid < 112) {
        const float* ri = Ts[gcl * 8 + PI[gp]];
        const float* rj = Ts[gcl * 8 + PJ[gp]];
        float s = 0.f;
#pragma unroll
        for (int c4 = 0; c4 < 64; c4 += 4) {
          float4 a = *reinterpret_cast<const float4*>(&ri[c4]);
          float4 b = *reinterpret_cast<const float4*>(&rj[c4]);
          s += a.x * b.x + a.y * b.y + a.z * b.z + a.w * b.w;
        }
        gacc += s;
      }
    }
    __syncthreads();   // Yhs block-i visible; Ts free for next step
  }
  if (isU) {
    if (tid < 112) Gram[((size_t)bid * 4 + gcl) * 28 + gp] = gacc;
  } else {
#pragma unroll
    for (int reg = 0; reg < 4; ++reg) {
      int rl = 16 * mi + kq * 4 + reg;
      atomicAdd(&asq[rl], sqs[reg]);
    }
    __syncthreads();
    if (tid < 32) aq[row0 - 512 + tid] = asq[tid];
  }
}

// GEMM2 (MFMA split-bf16, 2-pass) + per-block Cholesky prologue + fused epilogue.
__global__ __launch_bounds__(256) void k_mf2(const u16* __restrict__ Yh, const u16* __restrict__ Yl,
                                             const u16* __restrict__ Bh,
                                             const float* __restrict__ aq,
                                             const float* __restrict__ Gram,
                                             const float* __restrict__ S,
                                             float* __restrict__ out) {
  __shared__ float Csh[4][16][68];
  __shared__ float PRo[8][15], PRd[8][6], Psv[8][6], Pb[8], Ph[8];
  int tid = threadIdx.x, w = tid >> 6, lane = tid & 63;
  int m0 = blockIdx.x * 64 + w * 16;
  int bn = blockIdx.y * 64;
  int lr = lane & 15, kof = (lane >> 4) * 8;
  const u16* ah_p = Yh + (size_t)(m0 + lr) * D + kof;
  const u16* al_p = Yl + (size_t)(m0 + lr) * D + kof;
  const u16* bh_p = Bh + (size_t)(bn + lr) * D + kof;
  f4 acc[4];
#pragma unroll
  for (int nf = 0; nf < 4; ++nf) acc[nf] = (f4){0.f, 0.f, 0.f, 0.f};
#pragma unroll 2
  for (int k0 = 0; k0 < D; k0 += 32) {
    bf8 ah = *reinterpret_cast<const bf8*>(ah_p + k0);
    bf8 al = *reinterpret_cast<const bf8*>(al_p + k0);
    bf8 bh[4];
#pragma unroll
    for (int nf = 0; nf < 4; ++nf)
      bh[nf] = *reinterpret_cast<const bf8*>(bh_p + (size_t)nf * 16 * D + k0);
#pragma unroll
    for (int nf = 0; nf < 4; ++nf)
      acc[nf] = __builtin_amdgcn_mfma_f32_16x16x32_bf16(ah, bh[nf], acc[nf], 0, 0, 0);
#pragma unroll
    for (int nf = 0; nf < 4; ++nf)
      acc[nf] = __builtin_amdgcn_mfma_f32_16x16x32_bf16(al, bh[nf], acc[nf], 0, 0, 0);
  }
#pragma unroll
  for (int reg = 0; reg < 4; ++reg)
#pragma unroll
    for (int nf = 0; nf < 4; ++nf)
      Csh[w][((lane >> 4) << 2) + reg][nf * 16 + lr] = acc[nf][reg];
  if (tid < 8) {
    int c = blockIdx.y * 8 + tid;
    float Gv[28];
#pragma unroll
    for (int p = 0; p < 28; ++p) Gv[p] = Gram[c * 28 + p];
    float R[6][6];
    float logdetM = 0.f;
#pragma unroll
    for (int i = 0; i < 6; ++i) {
      float s = Gv[GIX(i, i)] + 1.f;
#pragma unroll
      for (int k = 0; k < i; ++k) s -= R[i][k] * R[i][k];
      float rii = sqrtf(s);
      R[i][i] = rii;
      logdetM += logf(rii);
      float inv = 1.f / rii;
      PRd[tid][i] = inv;
#pragma unroll
      for (int r = i + 1; r < 6; ++r) {
        float s2 = Gv[GIX(i, r)];
#pragma unroll
        for (int k = 0; k < i; ++k) s2 -= R[r][k] * R[i][k];
        R[r][i] = s2 * inv;
      }
    }
#pragma unroll
    for (int i = 1; i < 6; ++i)
#pragma unroll
      for (int k = 0; k < i; ++k)
        PRo[tid][i * (i - 1) / 2 + k] = R[i][k];
#pragma unroll
    for (int j = 0; j < 6; ++j) Psv[tid][j] = Gv[GIX(j, 6)];
    Ph[tid] = Gv[27];
    Pb[tid] = S[3] - 0.5f * (S[9] + 2.f * logdetM);
  }
  __syncthreads();
  float s8 = S[8], s10 = S[10], s11 = S[11];
  int r = lr;
  int q = m0 + r;
  float aqv = aq[q];
#pragma unroll
  for (int cc = 0; cc < 2; ++cc) {
    int cl = ((lane >> 4) << 1) + cc;
    const float* t = &Csh[w][r][cl * 8];
    float e[6];
#pragma unroll
    for (int j = 0; j < 6; ++j) e[j] = t[j] - Psv[cl][j];
    const float* o = PRo[cl];
    const float* dg = PRd[cl];
    float z0 = e[0] * dg[0];
    float z1 = (e[1] - o[0] * z0) * dg[1];
    float z2 = (e[2] - o[1] * z0 - o[2] * z1) * dg[2];
    float z3 = (e[3] - o[3] * z0 - o[4] * z1 - o[5] * z2) * dg[3];
    float z4 = (e[4] - o[6] * z0 - o[7] * z1 - o[8] * z2 - o[9] * z3) * dg[4];
    float z5 = (e[5] - o[10] * z0 - o[11] * z1 - o[12] * z2 - o[13] * z3 - o[14] * z4) * dg[5];
    float quad = z0 * z0 + z1 * z1 + z2 * z2 + z3 * z3 + z4 * z4 + z5 * z5;
    float dist = (aqv - 2.f * t[6] + Ph[cl] - quad) * s8;
    out[(size_t)q * NC + blockIdx.y * 8 + cl] = Pb[cl] - s10 * log1pf(dist * s11);
  }
}

extern "C" void kernel_launch(void* const* d_in, const int* in_sizes, int n_in,
                              void* d_out, int out_size, void* d_ws, size_t ws_size,
                              hipStream_t stream) {
  const float* Xs   = (const float*)d_in[0];
  const float* Xq   = (const float*)d_in[2];
  const float* m    = (const float*)d_in[3];
  const float* kap  = (const float*)d_in[4];
  const float* nu   = (const float*)d_in[5];
  const float* diag = (const float*)d_in[6];
  const float* low  = (const float*)d_in[7];
  float* ws = (float*)d_ws;

  float* S    = ws + OFF_S;
  u16*   Lh   = (u16*)(ws + OFF_LH);
  u16*   Ll   = (u16*)(ws + OFF_LL);
  u16*   DIh  = (u16*)(ws + OFF_DIH);
  u16*   DIl  = (u16*)(ws + OFF_DIL);
  u16*   YYh  = (u16*)(ws + OFF_YYH);
  u16*   YYl  = (u16*)(ws + OFF_YYL);
  float* aq   = ws + OFF_AQ;
  float* Gram = ws + OFF_GRAM;

  hipLaunchKernelGGL(k_prep, dim3(265), dim3(256), 0, stream,
                     diag, low, kap, nu, Lh, Ll, DIh, DIl, S);
  // build AB in-LDS + triangular solve + Gram/aq fusion (replaces solve+mf1)
  hipLaunchKernelGGL(k_fsolve, dim3(80), dim3(256), 0, stream,
                     Lh, Ll, DIh, DIl, Xs, Xq, m, kap, YYh, YYl, Gram, aq);
  // GEMM2: out = epilogue(Y @ UWp^T) with per-block Cholesky prologue
  hipLaunchKernelGGL(k_mf2, dim3(32, 8), dim3(256), 0, stream,
                     YYh + (size_t)512 * D, YYl + (size_t)512 * D, YYh,
                     aq, Gram, S, (float*)d_out);
}